// Round 9
// baseline (158.825 us; speedup 1.0000x reference)
//
#include <hip/hip_runtime.h>
#include <stdint.h>

#define HID 512
#define NH 8
#define HD 64
#define BB 4
#define SS 2048

typedef unsigned short u16;
typedef __attribute__((ext_vector_type(8))) short short8;
typedef __attribute__((ext_vector_type(4))) float f32x4;
typedef __attribute__((ext_vector_type(4))) _Float16 f16x4;
typedef __attribute__((ext_vector_type(8))) _Float16 f16x8;
typedef __attribute__((ext_vector_type(2))) unsigned int uint2v;
typedef __attribute__((ext_vector_type(4))) unsigned int uint4v;

#define MFMA16(a, b, c) __builtin_amdgcn_mfma_f32_16x16x32_bf16((a), (b), (c), 0, 0, 0)
#define MFMAH32(a, b, c) __builtin_amdgcn_mfma_f32_16x16x32_f16((a), (b), (c), 0, 0, 0)

// s_waitcnt encodings: lgkmcnt bits[11:8] | expcnt bits[6:4] | vmcnt low4
#define WAIT_VM4() __builtin_amdgcn_s_waitcnt(0xF74)
#define WAIT_VM3() __builtin_amdgcn_s_waitcnt(0xF73)
#define WAIT_VM0() __builtin_amdgcn_s_waitcnt(0xF70)
#define WAIT_VM4_LG0() __builtin_amdgcn_s_waitcnt(0x074)   // vmcnt(4) + lgkmcnt(0)
#define PIPE_BARRIER() do { asm volatile("" ::: "memory"); \
  __builtin_amdgcn_s_barrier(); asm volatile("" ::: "memory"); } while (0)

__device__ __forceinline__ u16 f2bf(float f) {
  union { float f; uint32_t u; } v; v.f = f;
  return (u16)((v.u + 0x7fffu + ((v.u >> 16) & 1u)) >> 16);
}

__device__ __forceinline__ u16 f2h(float f) {
  _Float16 h = (_Float16)f;
  return __builtin_bit_cast(u16, h);
}

__device__ __forceinline__ void gl_lds16(const u16* g, u16* l) {
  __builtin_amdgcn_global_load_lds(
      (const __attribute__((address_space(1))) unsigned int*)g,
      (__attribute__((address_space(3))) unsigned int*)l, 16, 0, 0);
}

// ---------------------------------------------------------------- prep
// 8 floats/thread (2x float4 -> 16B bf16 store). Grid 2560.
__global__ void prep(const float* __restrict__ x,
                     const float* __restrict__ w0, const float* __restrict__ w1,
                     const float* __restrict__ w2, const float* __restrict__ w3,
                     u16* __restrict__ xb,
                     u16* __restrict__ o0, u16* __restrict__ o1,
                     u16* __restrict__ o2, u16* __restrict__ o3) {
  const int bid = blockIdx.x;
  const float* in;
  u16* out;
  int base;
  if (bid < 2048) {
    in = x; out = xb; base = bid * 2048;
  } else {
    const int z = (bid - 2048) >> 7;
    base = ((bid - 2048) & 127) * 2048;
    in = (z == 0) ? w0 : (z == 1) ? w1 : (z == 2) ? w2 : w3;
    out = (z == 0) ? o0 : (z == 1) ? o1 : (z == 2) ? o2 : o3;
  }
  const int i = base + threadIdx.x * 8;
  float4 v0 = *(const float4*)(in + i);
  float4 v1 = *(const float4*)(in + i + 4);
  ushort4 a, b;
  a.x = f2bf(v0.x); a.y = f2bf(v0.y); a.z = f2bf(v0.z); a.w = f2bf(v0.w);
  b.x = f2bf(v1.x); b.y = f2bf(v1.y); b.z = f2bf(v1.z); b.w = f2bf(v1.w);
  *(ushort4*)(out + i) = a;
  *(ushort4*)(out + i + 4) = b;
}

// ---------------------------------------------------------------- QKV GEMM
// Ring-3 pipelined 128x128 tile, BK=32, 4 waves 2x2. Manual vmcnt + raw barrier.
// z=0 -> Q (bf16, scaled log2(e)/8) [B,H,S,D]; z=1 -> K (bf16) [B,H,S,D];
// z=2 -> V^T (f16) natively (A=Wv, B=x => C[o][r]).
// Epilogue: direct stores. (Staged-epilogue variants failed r3/r7/r8 with an
// unlocated systematic bug — concept abandoned.)
__global__ __launch_bounds__(256, 3)
void qkv_gemm(const u16* __restrict__ xb,
              const u16* __restrict__ wq, const u16* __restrict__ wk, const u16* __restrict__ wv,
              const float* __restrict__ bq, const float* __restrict__ bk, const float* __restrict__ bv,
              u16* __restrict__ Q, u16* __restrict__ K, u16* __restrict__ Vt) {
  __shared__ u16 sA[3][4096];
  __shared__ u16 sB[3][4096];
  const int tid = threadIdx.x;
  const int lane = tid & 63;
  const int wave = tid >> 6;
  const int l15 = lane & 15;
  const int quad = lane >> 4;
  const int wm = wave >> 1, wn = wave & 1;

  const int L = blockIdx.x;            // 0..767
  const int xcd = L & 7;
  const int slot = L >> 3;             // 0..95
  const int bm = xcd * 8 + (slot & 7); // 0..63
  const int r2 = slot >> 3;            // 0..11
  const int bn = r2 & 3;
  const int z = r2 >> 2;

  const float* bias = (z == 0) ? bq : (z == 1) ? bk : bv;
  const float scale = (z == 0) ? 0.18033688011112042f : 1.0f;  // log2(e)/8

  const u16* Arows = (z == 2) ? wv : xb;
  const u16* Brows = (z == 2) ? xb : ((z == 0) ? wq : wk);
  const int am0 = (z == 2) ? (bn * 128) : (bm * 128);
  const int bn0 = (z == 2) ? (bm * 128) : (bn * 128);

  const int srow = tid >> 2;
  const int sg = (tid & 3) ^ ((srow >> 1) & 3);
  const u16* gA = Arows + (am0 + srow) * 512 + sg * 8;
  const u16* gB = Brows + (bn0 + srow) * 512 + sg * 8;

  const int fsw = (quad ^ ((l15 >> 1) & 3)) * 8;
  int aoff[4], boff[4];
#pragma unroll
  for (int t = 0; t < 4; ++t) {
    aoff[t] = (wm * 64 + t * 16 + l15) * 32 + fsw;
    boff[t] = (wn * 64 + t * 16 + l15) * 32 + fsw;
  }

  f32x4 acc[4][4] = {};

#pragma unroll
  for (int t = 0; t < 2; ++t) {
    const int k0 = t * 32;
    gl_lds16(gA + k0, &sA[t][wave * 512]);
    gl_lds16(gA + k0 + 64 * 512, &sA[t][2048 + wave * 512]);
    gl_lds16(gB + k0, &sB[t][wave * 512]);
    gl_lds16(gB + k0 + 64 * 512, &sB[t][2048 + wave * 512]);
  }

  for (int kk = 0; kk < 16; ++kk) {
    WAIT_VM4();
    PIPE_BARRIER();
    {
      const int tp = (kk + 2 < 16) ? kk + 2 : 15;
      const int ns = (kk + 2) % 3;
      const int k0 = tp * 32;
      gl_lds16(gA + k0, &sA[ns][wave * 512]);
      gl_lds16(gA + k0 + 64 * 512, &sA[ns][2048 + wave * 512]);
      gl_lds16(gB + k0, &sB[ns][wave * 512]);
      gl_lds16(gB + k0 + 64 * 512, &sB[ns][2048 + wave * 512]);
    }
    const int cur = kk % 3;
    short8 af[4], bf[4];
#pragma unroll
    for (int t = 0; t < 4; ++t) af[t] = *(const short8*)&sA[cur][aoff[t]];
#pragma unroll
    for (int t = 0; t < 4; ++t) bf[t] = *(const short8*)&sB[cur][boff[t]];
#pragma unroll
    for (int mi = 0; mi < 4; ++mi)
#pragma unroll
      for (int ni = 0; ni < 4; ++ni)
        acc[mi][ni] = MFMA16(af[mi], bf[ni], acc[mi][ni]);
  }

  if (z != 2) {
    u16* dst = (z == 0) ? Q : K;
#pragma unroll
    for (int mi = 0; mi < 4; ++mi) {
#pragma unroll
      for (int ni = 0; ni < 4; ++ni) {
        const int col = bn0 + wn * 64 + ni * 16 + l15;
        const float bs = bias[col];
#pragma unroll
        for (int i = 0; i < 4; ++i) {
          const int row = am0 + wm * 64 + mi * 16 + quad * 4 + i;
          const float v = (acc[mi][ni][i] + bs) * scale;
          const int b = row >> 11, s = row & 2047;
          const int h = col >> 6, d = col & 63;
          dst[(((size_t)(b * 8 + h) * 2048 + s) << 6) + d] = f2bf(v);
        }
      }
    }
  } else {
#pragma unroll
    for (int mi = 0; mi < 4; ++mi) {
#pragma unroll
      for (int i = 0; i < 4; ++i) {
        const int o = am0 + wm * 64 + mi * 16 + quad * 4 + i;
        const float bs = bias[o];
        const int h = o >> 6, d = o & 63;
#pragma unroll
        for (int ni = 0; ni < 4; ++ni) {
          const int r = bn0 + wn * 64 + ni * 16 + l15;
          const int b = r >> 11, s = r & 2047;
          Vt[(((size_t)(b * 8 + h) * 64 + d) << 11) + s] = f2h(acc[mi][ni][i] + bs);
        }
      }
    }
  }
}

// ---------------------------------------------------------------- attention
// S^T-trick flash attention, ring-4, quad-interleaved t-strips (r6 structure,
// proven <43.2us). NEW (r9): 1-tile-deep software pipeline — psacc/pvraw carry
// tile tt-1's scores + V-frags in registers; per iteration the softmax+PV of
// tt-1 (register-only VALU+MFMA) overlaps tile tt's ds_reads and sacc MFMAs,
// breaking the per-tile sacc->exp2->PV serial chain (T15 analog, +8-11%
// measured on attn-shaped kernels). Top-of-loop wait is vmcnt(4)+lgkmcnt(0):
// all prior ds_reads complete before the prefetch that recycles their ring
// slot is issued (slot (tt+3)&3 == slot (tt-1)&3).
__global__ __launch_bounds__(512, 4)
void attn(const u16* __restrict__ Q, const u16* __restrict__ K,
          const u16* __restrict__ Vt, u16* __restrict__ ctx) {
  __shared__ __align__(16) u16 smem[4 * 8192];  // slot: K[64t][64d] @0, V[64d][64t] @4096
  const int tid = threadIdx.x;
  const int lane = tid & 63;
  const int wave = tid >> 6;
  const int l15 = lane & 15;
  const int quad = lane >> 4;
  const int pair = wave >> 1;   // 0..3: rows pair*32..+31
  const int par = wave & 1;     // t-strip parity

  const int L = blockIdx.x;           // 0..511
  const int xcd = L & 7;
  const int slotb = L >> 3;
  const int bh = xcd * 4 + (slotb & 3);
  const int qt = slotb >> 2;          // 0..15

  const u16* Qb = Q + (size_t)bh * SS * HD;
  const u16* Kb = K + (size_t)bh * SS * HD;
  const u16* Vb = Vt + (size_t)bh * HD * SS;

  // Q B-fragments (regs): qrow = rowbase + rf*16 + l15, d = kc*32 + quad*8
  const int rowbase = qt * 128 + pair * 32;
  short8 qf[2][2];
#pragma unroll
  for (int rf = 0; rf < 2; ++rf)
#pragma unroll
    for (int kc = 0; kc < 2; ++kc)
      qf[rf][kc] = *(const short8*)(Qb + (rowbase + rf * 16 + l15) * 64 + kc * 32 + quad * 8);
  asm volatile("" ::: "memory");  // Q loads oldest in vmcnt queue

  f32x4 oacc[2][4] = {};
  float plsum[2] = {0.f, 0.f};

  // DMA source offsets (swizzle on the global side; LDS dest is linear tid*8)
  const int trow = tid >> 3;                    // 0..63
  const int rK = (trow & 3) | (((trow >> 3) & 1) << 2);   // K row-hash
  const int gswK = (tid & 7) ^ rK;
  const int gswV = (tid & 7) ^ (trow & 7);
  const int kOff = trow * 64 + gswK * 8;        // + tile*4096
  const int vOff = trow * 2048 + gswV * 8;      // + tile*64
  u16* ldsK = smem + tid * 8;                   // + slot*8192
  u16* ldsV = smem + 4096 + tid * 8;

  // fragment LDS offsets (u16 units)
  const int l7 = l15 & 7;
  // K: strip s, kc: row tK = par*32 + (l15>>2)*8 + (l15&3) + 4s; chunk = (kc*4+quad)^r(tK),
  // and r(tK) == l7 for these rows.
  const int tKbase = par * 32 + ((l15 >> 2) * 8) + (l15 & 3);
  int kfo[2][2];
#pragma unroll
  for (int s = 0; s < 2; ++s)
#pragma unroll
    for (int kc = 0; kc < 2; ++kc)
      kfo[s][kc] = (tKbase + 4 * s) * 64 + (((kc * 4 + quad) ^ l7) * 8);
  // V (K=32 B-frag): row d = nd*16 + l15 (+nd*1024 at use), t-granule par*4+quad, b128
  const int vfoV = l15 * 64 + (((par * 4 + quad) ^ l7) * 8);

  // preload tiles 0..2
#pragma unroll
  for (int t = 0; t < 3; ++t) {
    gl_lds16(Kb + t * 4096 + kOff, ldsK + t * 8192);
    gl_lds16(Vb + t * 64 + vOff, ldsV + t * 8192);
  }

  // pipeline state: tile tt-1's scores and V-fragments (registers)
  f32x4 psacc[2][2];
  short8 pvraw[4];

  // ---- prologue: tile 0 -> psacc/pvraw (no softmax yet)
  {
    WAIT_VM4_LG0();
    PIPE_BARRIER();
    gl_lds16(Kb + 3 * 4096 + kOff, ldsK + 3 * 8192);
    gl_lds16(Vb + 3 * 64 + vOff, ldsV + 3 * 8192);
    short8 ks[2][2];
#pragma unroll
    for (int s = 0; s < 2; ++s)
#pragma unroll
      for (int kc = 0; kc < 2; ++kc)
        ks[s][kc] = *(const short8*)&smem[kfo[s][kc]];
    f32x4 ns[2][2] = {};
    __builtin_amdgcn_s_setprio(1);
#pragma unroll
    for (int s = 0; s < 2; ++s)
#pragma unroll
      for (int rf = 0; rf < 2; ++rf) {
        ns[s][rf] = MFMA16(ks[s][0], qf[rf][0], ns[s][rf]);
        ns[s][rf] = MFMA16(ks[s][1], qf[rf][1], ns[s][rf]);
      }
    __builtin_amdgcn_s_setprio(0);
#pragma unroll
    for (int s = 0; s < 2; ++s)
#pragma unroll
      for (int rf = 0; rf < 2; ++rf) psacc[s][rf] = ns[s][rf];
#pragma unroll
    for (int nd = 0; nd < 4; ++nd)
      pvraw[nd] = *(const short8*)&smem[4096 + nd * 1024 + vfoV];
  }

  for (int tt = 1; tt < 32; ++tt) {
    WAIT_VM4_LG0();     // tile tt landed; ALL our ds_reads (incl. pvraw) done
    PIPE_BARRIER();
    {
      const int tp = (tt + 3 < 32) ? tt + 3 : 31;   // clamp -> harmless dup
      const int ns2 = (tt + 3) & 3;
      gl_lds16(Kb + tp * 4096 + kOff, ldsK + ns2 * 8192);
      gl_lds16(Vb + tp * 64 + vOff, ldsV + ns2 * 8192);
    }
    const int cb = (tt & 3) * 8192;

    // issue tile tt's K-frag reads early (complete under the VALU block below)
    short8 ks[2][2];
#pragma unroll
    for (int s = 0; s < 2; ++s)
#pragma unroll
      for (int kc = 0; kc < 2; ++kc)
        ks[s][kc] = *(const short8*)&smem[cb + kfo[s][kc]];

    // ---- softmax + PV of tile tt-1 (pure registers: psacc, pvraw)
#pragma unroll
    for (int rf = 0; rf < 2; ++rf) {
      const float p0 = __builtin_amdgcn_exp2f(psacc[0][rf][0]);
      const float p1 = __builtin_amdgcn_exp2f(psacc[0][rf][1]);
      const float p2 = __builtin_amdgcn_exp2f(psacc[0][rf][2]);
      const float p3 = __builtin_amdgcn_exp2f(psacc[0][rf][3]);
      const float p4 = __builtin_amdgcn_exp2f(psacc[1][rf][0]);
      const float p5 = __builtin_amdgcn_exp2f(psacc[1][rf][1]);
      const float p6 = __builtin_amdgcn_exp2f(psacc[1][rf][2]);
      const float p7 = __builtin_amdgcn_exp2f(psacc[1][rf][3]);
      plsum[rf] += ((p0 + p1) + (p2 + p3)) + ((p4 + p5) + (p6 + p7));
      uint4v pw;
      pw.x = __builtin_bit_cast(unsigned int, __builtin_amdgcn_cvt_pkrtz(p0, p1));
      pw.y = __builtin_bit_cast(unsigned int, __builtin_amdgcn_cvt_pkrtz(p2, p3));
      pw.z = __builtin_bit_cast(unsigned int, __builtin_amdgcn_cvt_pkrtz(p4, p5));
      pw.w = __builtin_bit_cast(unsigned int, __builtin_amdgcn_cvt_pkrtz(p6, p7));
      const f16x8 pf = __builtin_bit_cast(f16x8, pw);
#pragma unroll
      for (int nd = 0; nd < 4; ++nd)
        oacc[rf][nd] = MFMAH32(pf, __builtin_bit_cast(f16x8, pvraw[nd]), oacc[rf][nd]);
    }

    // ---- scores for tile tt
    f32x4 nsacc[2][2] = {};
    __builtin_amdgcn_s_setprio(1);
#pragma unroll
    for (int s = 0; s < 2; ++s)
#pragma unroll
      for (int rf = 0; rf < 2; ++rf) {
        nsacc[s][rf] = MFMA16(ks[s][0], qf[rf][0], nsacc[s][rf]);
        nsacc[s][rf] = MFMA16(ks[s][1], qf[rf][1], nsacc[s][rf]);
      }
    __builtin_amdgcn_s_setprio(0);

    // ---- rotate pipeline state (pvraw reads issued after psacc/pvraw dead)
#pragma unroll
    for (int s = 0; s < 2; ++s)
#pragma unroll
      for (int rf = 0; rf < 2; ++rf) psacc[s][rf] = nsacc[s][rf];
#pragma unroll
    for (int nd = 0; nd < 4; ++nd)
      pvraw[nd] = *(const short8*)&smem[cb + 4096 + nd * 1024 + vfoV];
  }

  // ---- epilogue: softmax + PV of tile 31
  {
    WAIT_VM0();  // also covers dup DMAs; lgkm waits inserted by compiler for pvraw
#pragma unroll
    for (int rf = 0; rf < 2; ++rf) {
      const float p0 = __builtin_amdgcn_exp2f(psacc[0][rf][0]);
      const float p1 = __builtin_amdgcn_exp2f(psacc[0][rf][1]);
      const float p2 = __builtin_amdgcn_exp2f(psacc[0][rf][2]);
      const float p3 = __builtin_amdgcn_exp2f(psacc[0][rf][3]);
      const float p4 = __builtin_amdgcn_exp2f(psacc[1][rf][0]);
      const float p5 = __builtin_amdgcn_exp2f(psacc[1][rf][1]);
      const float p6 = __builtin_amdgcn_exp2f(psacc[1][rf][2]);
      const float p7 = __builtin_amdgcn_exp2f(psacc[1][rf][3]);
      plsum[rf] += ((p0 + p1) + (p2 + p3)) + ((p4 + p5) + (p6 + p7));
      uint4v pw;
      pw.x = __builtin_bit_cast(unsigned int, __builtin_amdgcn_cvt_pkrtz(p0, p1));
      pw.y = __builtin_bit_cast(unsigned int, __builtin_amdgcn_cvt_pkrtz(p2, p3));
      pw.z = __builtin_bit_cast(unsigned int, __builtin_amdgcn_cvt_pkrtz(p4, p5));
      pw.w = __builtin_bit_cast(unsigned int, __builtin_amdgcn_cvt_pkrtz(p6, p7));
      const f16x8 pf = __builtin_bit_cast(f16x8, pw);
#pragma unroll
      for (int nd = 0; nd < 4; ++nd)
        oacc[rf][nd] = MFMAH32(pf, __builtin_bit_cast(f16x8, pvraw[nd]), oacc[rf][nd]);
    }
  }

  __syncthreads();   // all DMAs drained above; smem reusable

  // reduce partial row sums across quads: lane l15 -> sum for qrow rf*16+l15
#pragma unroll
  for (int rf = 0; rf < 2; ++rf) {
    plsum[rf] += __shfl_xor(plsum[rf], 16);
    plsum[rf] += __shfl_xor(plsum[rf], 32);
  }

  float* cbuf = (float*)smem;          // [128 rows][68]
  float* lbuf = cbuf + 128 * 68;       // [128]
  if (par) {
#pragma unroll
    for (int rf = 0; rf < 2; ++rf) {
#pragma unroll
      for (int nd = 0; nd < 4; ++nd)
#pragma unroll
        for (int i = 0; i < 4; ++i)
          cbuf[(pair * 32 + rf * 16 + quad * 4 + i) * 68 + nd * 16 + l15] = oacc[rf][nd][i];
      if (quad == 0) lbuf[pair * 32 + rf * 16 + l15] = plsum[rf];
    }
  }
  __syncthreads();
  if (!par) {
    const int b = bh >> 3, h = bh & 7;
#pragma unroll
    for (int rf = 0; rf < 2; ++rf) {
      const float tot = plsum[rf] + lbuf[pair * 32 + rf * 16 + l15];
      float inv[4];
#pragma unroll
      for (int i = 0; i < 4; ++i)
        inv[i] = __builtin_amdgcn_rcpf(__shfl(tot, quad * 4 + i));
#pragma unroll
      for (int nd = 0; nd < 4; ++nd)
#pragma unroll
        for (int i = 0; i < 4; ++i) {
          const float v = (oacc[rf][nd][i] +
                           cbuf[(pair * 32 + rf * 16 + quad * 4 + i) * 68 + nd * 16 + l15]) * inv[i];
          const int s = rowbase + rf * 16 + quad * 4 + i;
          const int d = nd * 16 + l15;
          ctx[((size_t)(b * 2048 + s) << 9) + h * 64 + d] = f2bf(v);
        }
    }
  }
}

// ---------------------------------------------------------------- out GEMM
// Ring-3 pipelined 128x64 tiles; manual vmcnt(3) + raw barrier; XCD-clustered bm.
// Epilogue: direct stores (proven r0-r6).
__global__ __launch_bounds__(256, 2)
void out_gemm(const u16* __restrict__ A, const u16* __restrict__ W,
              const float* __restrict__ bias, float* __restrict__ out) {
  __shared__ u16 sA[3][4096];
  __shared__ u16 sB[3][2048];
  const int tid = threadIdx.x;
  const int lane = tid & 63;
  const int wave = tid >> 6;
  const int l15 = lane & 15;
  const int quad = lane >> 4;

  const int L = blockIdx.x;
  const int xcd = L & 7;
  const int slot = L >> 3;
  const int bm = xcd * 8 + (slot & 7);
  const int bn = slot >> 3;

  const int srow = tid >> 2;
  const int sg = (tid & 3) ^ ((srow >> 1) & 3);
  const u16* gA = A + (bm * 128 + srow) * 512 + sg * 8;
  const u16* gB = W + (bn * 64 + srow) * 512 + sg * 8;

  const int fsw = (quad ^ ((l15 >> 1) & 3)) * 8;
  int aoff[2], boff[4];
#pragma unroll
  for (int t = 0; t < 2; ++t) aoff[t] = (wave * 32 + t * 16 + l15) * 32 + fsw;
#pragma unroll
  for (int t = 0; t < 4; ++t) boff[t] = (t * 16 + l15) * 32 + fsw;

  f32x4 acc[2][4] = {};

#pragma unroll
  for (int t = 0; t < 2; ++t) {
    const int k0 = t * 32;
    gl_lds16(gA + k0, &sA[t][wave * 512]);
    gl_lds16(gA + k0 + 64 * 512, &sA[t][2048 + wave * 512]);
    gl_lds16(gB + k0, &sB[t][wave * 512]);
  }

  for (int kk = 0; kk < 16; ++kk) {
    WAIT_VM3();
    PIPE_BARRIER();
    {
      const int tp = (kk + 2 < 16) ? kk + 2 : 15;
      const int ns = (kk + 2) % 3;
      const int k0 = tp * 32;
      gl_lds16(gA + k0, &sA[ns][wave * 512]);
      gl_lds16(gA + k0 + 64 * 512, &sA[ns][2048 + wave * 512]);
      gl_lds16(gB + k0, &sB[ns][wave * 512]);
    }
    const int cur = kk % 3;
    short8 af[2], bf[4];
#pragma unroll
    for (int t = 0; t < 2; ++t) af[t] = *(const short8*)&sA[cur][aoff[t]];
#pragma unroll
    for (int t = 0; t < 4; ++t) bf[t] = *(const short8*)&sB[cur][boff[t]];
#pragma unroll
    for (int mi = 0; mi < 2; ++mi)
#pragma unroll
      for (int ni = 0; ni < 4; ++ni)
        acc[mi][ni] = MFMA16(af[mi], bf[ni], acc[mi][ni]);
  }

#pragma unroll
  for (int mi = 0; mi < 2; ++mi) {
#pragma unroll
    for (int ni = 0; ni < 4; ++ni) {
      const int col = bn * 64 + ni * 16 + l15;
      const float bs = bias[col];
#pragma unroll
      for (int i = 0; i < 4; ++i) {
        const int row = bm * 128 + wave * 32 + mi * 16 + quad * 4 + i;
        out[(size_t)row * 512 + col] = acc[mi][ni][i] + bs;
      }
    }
  }
}

// ---------------------------------------------------------------- launch
extern "C" void kernel_launch(void* const* d_in, const int* in_sizes, int n_in,
                              void* d_out, int out_size, void* d_ws, size_t ws_size,
                              hipStream_t stream) {
  const float* x = (const float*)d_in[0];
  const float* Wq = (const float*)d_in[1];
  const float* bq = (const float*)d_in[2];
  const float* Wk = (const float*)d_in[3];
  const float* bk = (const float*)d_in[4];
  const float* Wv = (const float*)d_in[5];
  const float* bv = (const float*)d_in[6];
  const float* Wo = (const float*)d_in[7];
  const float* bo = (const float*)d_in[8];
  float* out = (float*)d_out;

  char* ws = (char*)d_ws;
  u16* xb  = (u16*)(ws);                               // 8 MiB
  u16* wqb = (u16*)(ws + (8u << 20));                  // 512 KiB each
  u16* wkb = (u16*)(ws + (8u << 20) + (512u << 10));
  u16* wvb = (u16*)(ws + (9u << 20));
  u16* wob = (u16*)(ws + (9u << 20) + (512u << 10));
  u16* Qb  = (u16*)(ws + (10u << 20));                 // 8 MiB [B,H,S,D] bf16 * log2e/8
  u16* Kb  = (u16*)(ws + (18u << 20));                 // 8 MiB [B,H,S,D] bf16
  u16* Vtb = (u16*)(ws + (26u << 20));                 // 8 MiB [B,H,D,S] f16
  u16* ctx = (u16*)(ws + (34u << 20));                 // 8 MiB [B,S,HID] bf16

  prep<<<2560, 256, 0, stream>>>(x, Wq, Wk, Wv, Wo, xb, wqb, wkb, wvb, wob);
  qkv_gemm<<<768, 256, 0, stream>>>(xb, wqb, wkb, wvb, bq, bk, bv, Qb, Kb, Vtb);
  attn<<<512, 512, 0, stream>>>(Qb, Kb, Vtb, ctx);
  out_gemm<<<512, 256, 0, stream>>>(ctx, wob, bo, out);
}

// Round 10
// 154.979 us; speedup vs baseline: 1.0248x; 1.0248x over previous
//
#include <hip/hip_runtime.h>
#include <stdint.h>

#define HID 512
#define NH 8
#define HD 64
#define BB 4
#define SS 2048

typedef unsigned short u16;
typedef __attribute__((ext_vector_type(8))) short short8;
typedef __attribute__((ext_vector_type(4))) float f32x4;
typedef __attribute__((ext_vector_type(4))) _Float16 f16x4;
typedef __attribute__((ext_vector_type(8))) _Float16 f16x8;
typedef __attribute__((ext_vector_type(2))) unsigned int uint2v;
typedef __attribute__((ext_vector_type(4))) unsigned int uint4v;

#define MFMA16(a, b, c) __builtin_amdgcn_mfma_f32_16x16x32_bf16((a), (b), (c), 0, 0, 0)
#define MFMAH32(a, b, c) __builtin_amdgcn_mfma_f32_16x16x32_f16((a), (b), (c), 0, 0, 0)

// s_waitcnt encodings: lgkmcnt bits[11:8] | expcnt bits[6:4] | vmcnt low4
#define WAIT_VM4() __builtin_amdgcn_s_waitcnt(0xF74)
#define WAIT_VM3() __builtin_amdgcn_s_waitcnt(0xF73)
#define WAIT_VM0() __builtin_amdgcn_s_waitcnt(0xF70)
#define PIPE_BARRIER() do { asm volatile("" ::: "memory"); \
  __builtin_amdgcn_s_barrier(); asm volatile("" ::: "memory"); } while (0)

__device__ __forceinline__ u16 f2bf(float f) {
  union { float f; uint32_t u; } v; v.f = f;
  return (u16)((v.u + 0x7fffu + ((v.u >> 16) & 1u)) >> 16);
}

__device__ __forceinline__ u16 f2h(float f) {
  _Float16 h = (_Float16)f;
  return __builtin_bit_cast(u16, h);
}

__device__ __forceinline__ void gl_lds16(const u16* g, u16* l) {
  __builtin_amdgcn_global_load_lds(
      (const __attribute__((address_space(1))) unsigned int*)g,
      (__attribute__((address_space(3))) unsigned int*)l, 16, 0, 0);
}

__device__ __forceinline__ void gl_lds4(const u16* g, u16* l) {
  __builtin_amdgcn_global_load_lds(
      (const __attribute__((address_space(1))) unsigned int*)g,
      (__attribute__((address_space(3))) unsigned int*)l, 4, 0, 0);
}

// ---------------------------------------------------------------- prep
// 8 floats/thread (2x float4 -> 16B bf16 store). Grid 2560.
__global__ void prep(const float* __restrict__ x,
                     const float* __restrict__ w0, const float* __restrict__ w1,
                     const float* __restrict__ w2, const float* __restrict__ w3,
                     u16* __restrict__ xb,
                     u16* __restrict__ o0, u16* __restrict__ o1,
                     u16* __restrict__ o2, u16* __restrict__ o3) {
  const int bid = blockIdx.x;
  const float* in;
  u16* out;
  int base;
  if (bid < 2048) {
    in = x; out = xb; base = bid * 2048;
  } else {
    const int z = (bid - 2048) >> 7;
    base = ((bid - 2048) & 127) * 2048;
    in = (z == 0) ? w0 : (z == 1) ? w1 : (z == 2) ? w2 : w3;
    out = (z == 0) ? o0 : (z == 1) ? o1 : (z == 2) ? o2 : o3;
  }
  const int i = base + threadIdx.x * 8;
  float4 v0 = *(const float4*)(in + i);
  float4 v1 = *(const float4*)(in + i + 4);
  ushort4 a, b;
  a.x = f2bf(v0.x); a.y = f2bf(v0.y); a.z = f2bf(v0.z); a.w = f2bf(v0.w);
  b.x = f2bf(v1.x); b.y = f2bf(v1.y); b.z = f2bf(v1.z); b.w = f2bf(v1.w);
  *(ushort4*)(out + i) = a;
  *(ushort4*)(out + i + 4) = b;
}

// ---------------------------------------------------------------- QKV GEMM
// Ring-3 pipelined 128x128 tile, BK=32, 4 waves 2x2. Manual vmcnt + raw barrier.
// z=0 -> Q (bf16, scaled log2(e)/8) [B,H,S,D]; z=1 -> K (bf16) [B,H,S,D];
// z=2 -> V^T (f16) natively (A=Wv, B=x => C[o][r]).
// Epilogue: direct stores (proven; staged variants failed r3/r7/r8 — abandoned).
__global__ __launch_bounds__(256, 3)
void qkv_gemm(const u16* __restrict__ xb,
              const u16* __restrict__ wq, const u16* __restrict__ wk, const u16* __restrict__ wv,
              const float* __restrict__ bq, const float* __restrict__ bk, const float* __restrict__ bv,
              u16* __restrict__ Q, u16* __restrict__ K, u16* __restrict__ Vt) {
  __shared__ u16 sA[3][4096];
  __shared__ u16 sB[3][4096];
  const int tid = threadIdx.x;
  const int lane = tid & 63;
  const int wave = tid >> 6;
  const int l15 = lane & 15;
  const int quad = lane >> 4;
  const int wm = wave >> 1, wn = wave & 1;

  const int L = blockIdx.x;            // 0..767
  const int xcd = L & 7;
  const int slot = L >> 3;             // 0..95
  const int bm = xcd * 8 + (slot & 7); // 0..63
  const int r2 = slot >> 3;            // 0..11
  const int bn = r2 & 3;
  const int z = r2 >> 2;

  const float* bias = (z == 0) ? bq : (z == 1) ? bk : bv;
  const float scale = (z == 0) ? 0.18033688011112042f : 1.0f;  // log2(e)/8

  const u16* Arows = (z == 2) ? wv : xb;
  const u16* Brows = (z == 2) ? xb : ((z == 0) ? wq : wk);
  const int am0 = (z == 2) ? (bn * 128) : (bm * 128);
  const int bn0 = (z == 2) ? (bm * 128) : (bn * 128);

  const int srow = tid >> 2;
  const int sg = (tid & 3) ^ ((srow >> 1) & 3);
  const u16* gA = Arows + (am0 + srow) * 512 + sg * 8;
  const u16* gB = Brows + (bn0 + srow) * 512 + sg * 8;

  const int fsw = (quad ^ ((l15 >> 1) & 3)) * 8;
  int aoff[4], boff[4];
#pragma unroll
  for (int t = 0; t < 4; ++t) {
    aoff[t] = (wm * 64 + t * 16 + l15) * 32 + fsw;
    boff[t] = (wn * 64 + t * 16 + l15) * 32 + fsw;
  }

  f32x4 acc[4][4] = {};

#pragma unroll
  for (int t = 0; t < 2; ++t) {
    const int k0 = t * 32;
    gl_lds16(gA + k0, &sA[t][wave * 512]);
    gl_lds16(gA + k0 + 64 * 512, &sA[t][2048 + wave * 512]);
    gl_lds16(gB + k0, &sB[t][wave * 512]);
    gl_lds16(gB + k0 + 64 * 512, &sB[t][2048 + wave * 512]);
  }

  for (int kk = 0; kk < 16; ++kk) {
    WAIT_VM4();
    PIPE_BARRIER();
    {
      const int tp = (kk + 2 < 16) ? kk + 2 : 15;
      const int ns = (kk + 2) % 3;
      const int k0 = tp * 32;
      gl_lds16(gA + k0, &sA[ns][wave * 512]);
      gl_lds16(gA + k0 + 64 * 512, &sA[ns][2048 + wave * 512]);
      gl_lds16(gB + k0, &sB[ns][wave * 512]);
      gl_lds16(gB + k0 + 64 * 512, &sB[ns][2048 + wave * 512]);
    }
    const int cur = kk % 3;
    short8 af[4], bf[4];
#pragma unroll
    for (int t = 0; t < 4; ++t) af[t] = *(const short8*)&sA[cur][aoff[t]];
#pragma unroll
    for (int t = 0; t < 4; ++t) bf[t] = *(const short8*)&sB[cur][boff[t]];
#pragma unroll
    for (int mi = 0; mi < 4; ++mi)
#pragma unroll
      for (int ni = 0; ni < 4; ++ni)
        acc[mi][ni] = MFMA16(af[mi], bf[ni], acc[mi][ni]);
  }

  if (z != 2) {
    u16* dst = (z == 0) ? Q : K;
#pragma unroll
    for (int mi = 0; mi < 4; ++mi) {
#pragma unroll
      for (int ni = 0; ni < 4; ++ni) {
        const int col = bn0 + wn * 64 + ni * 16 + l15;
        const float bs = bias[col];
#pragma unroll
        for (int i = 0; i < 4; ++i) {
          const int row = am0 + wm * 64 + mi * 16 + quad * 4 + i;
          const float v = (acc[mi][ni][i] + bs) * scale;
          const int b = row >> 11, s = row & 2047;
          const int h = col >> 6, d = col & 63;
          dst[(((size_t)(b * 8 + h) * 2048 + s) << 6) + d] = f2bf(v);
        }
      }
    }
  } else {
#pragma unroll
    for (int mi = 0; mi < 4; ++mi) {
#pragma unroll
      for (int i = 0; i < 4; ++i) {
        const int o = am0 + wm * 64 + mi * 16 + quad * 4 + i;
        const float bs = bias[o];
        const int h = o >> 6, d = o & 63;
#pragma unroll
        for (int ni = 0; ni < 4; ++ni) {
          const int r = bn0 + wn * 64 + ni * 16 + l15;
          const int b = r >> 11, s = r & 2047;
          Vt[(((size_t)(b * 8 + h) * 64 + d) << 11) + s] = f2h(acc[mi][ni][i] + bs);
        }
      }
    }
  }
}

// ---------------------------------------------------------------- attention
// S^T-trick flash attention, ring-4 (vmcnt(4)+barrier per tile). Quad-
// interleaved t-strips: PV uses K=32 f16 MFMA (8 issues) and 4x b128 V-reads.
// (r6 version — proven <43.2us; r9's 1-deep pipeline was neutral, reverted.)
__global__ __launch_bounds__(512, 4)
void attn(const u16* __restrict__ Q, const u16* __restrict__ K,
          const u16* __restrict__ Vt, u16* __restrict__ ctx) {
  __shared__ __align__(16) u16 smem[4 * 8192];  // slot: K[64t][64d] @0, V[64d][64t] @4096
  const int tid = threadIdx.x;
  const int lane = tid & 63;
  const int wave = tid >> 6;
  const int l15 = lane & 15;
  const int quad = lane >> 4;
  const int pair = wave >> 1;   // 0..3: rows pair*32..+31
  const int par = wave & 1;     // t-strip parity

  const int L = blockIdx.x;           // 0..511
  const int xcd = L & 7;
  const int slotb = L >> 3;
  const int bh = xcd * 4 + (slotb & 3);
  const int qt = slotb >> 2;          // 0..15

  const u16* Qb = Q + (size_t)bh * SS * HD;
  const u16* Kb = K + (size_t)bh * SS * HD;
  const u16* Vb = Vt + (size_t)bh * HD * SS;

  // Q B-fragments (regs): qrow = rowbase + rf*16 + l15, d = kc*32 + quad*8
  const int rowbase = qt * 128 + pair * 32;
  short8 qf[2][2];
#pragma unroll
  for (int rf = 0; rf < 2; ++rf)
#pragma unroll
    for (int kc = 0; kc < 2; ++kc)
      qf[rf][kc] = *(const short8*)(Qb + (rowbase + rf * 16 + l15) * 64 + kc * 32 + quad * 8);
  asm volatile("" ::: "memory");  // Q loads oldest in vmcnt queue

  f32x4 oacc[2][4] = {};
  float plsum[2] = {0.f, 0.f};

  // DMA source offsets (swizzle on the global side; LDS dest is linear tid*8)
  const int trow = tid >> 3;                    // 0..63
  const int rK = (trow & 3) | (((trow >> 3) & 1) << 2);   // K row-hash
  const int gswK = (tid & 7) ^ rK;
  const int gswV = (tid & 7) ^ (trow & 7);
  const int kOff = trow * 64 + gswK * 8;        // + tile*4096
  const int vOff = trow * 2048 + gswV * 8;      // + tile*64
  u16* ldsK = smem + tid * 8;                   // + slot*8192
  u16* ldsV = smem + 4096 + tid * 8;

  // fragment LDS offsets (u16 units)
  const int l7 = l15 & 7;
  // K: strip s, kc: row tK = par*32 + (l15>>2)*8 + (l15&3) + 4s; chunk = (kc*4+quad)^r(tK),
  // and r(tK) == l7 for these rows.
  const int tKbase = par * 32 + ((l15 >> 2) * 8) + (l15 & 3);
  int kfo[2][2];
#pragma unroll
  for (int s = 0; s < 2; ++s)
#pragma unroll
    for (int kc = 0; kc < 2; ++kc)
      kfo[s][kc] = (tKbase + 4 * s) * 64 + (((kc * 4 + quad) ^ l7) * 8);
  // V (K=32 B-frag): row d = nd*16 + l15 (+nd*1024 at use), t-granule par*4+quad, b128
  const int vfoV = l15 * 64 + (((par * 4 + quad) ^ l7) * 8);

  // preload tiles 0..2
#pragma unroll
  for (int t = 0; t < 3; ++t) {
    gl_lds16(Kb + t * 4096 + kOff, ldsK + t * 8192);
    gl_lds16(Vb + t * 64 + vOff, ldsV + t * 8192);
  }

  for (int tt = 0; tt < 32; ++tt) {
    WAIT_VM4();      // retires exactly tile tt (leaves tt+1, tt+2 in flight)
    PIPE_BARRIER();
    {
      const int tp = (tt + 3 < 32) ? tt + 3 : 31;   // clamp -> harmless dup
      const int ns = (tt + 3) & 3;
      gl_lds16(Kb + tp * 4096 + kOff, ldsK + ns * 8192);
      gl_lds16(Vb + tp * 64 + vOff, ldsV + ns * 8192);
    }
    const int cb = (tt & 3) * 8192;

    // S^T for both interleaved strips: sacc[s][rf][i] = S[t=par*32+quad*8+i+4s][q=rf*16+l15]
    short8 ks[2][2];
#pragma unroll
    for (int s = 0; s < 2; ++s)
#pragma unroll
      for (int kc = 0; kc < 2; ++kc)
        ks[s][kc] = *(const short8*)&smem[cb + kfo[s][kc]];
    f32x4 sacc[2][2] = {};
    __builtin_amdgcn_s_setprio(1);
#pragma unroll
    for (int s = 0; s < 2; ++s)
#pragma unroll
      for (int rf = 0; rf < 2; ++rf) {
        sacc[s][rf] = MFMA16(ks[s][0], qf[rf][0], sacc[s][rf]);
        sacc[s][rf] = MFMA16(ks[s][1], qf[rf][1], sacc[s][rf]);
      }
    __builtin_amdgcn_s_setprio(0);
    // V B-frags (K=32): 4x b128
    short8 vraw[4];
#pragma unroll
    for (int nd = 0; nd < 4; ++nd)
      vraw[nd] = *(const short8*)&smem[cb + 4096 + nd * 1024 + vfoV];
#pragma unroll
    for (int rf = 0; rf < 2; ++rf) {
      const float p0 = __builtin_amdgcn_exp2f(sacc[0][rf][0]);
      const float p1 = __builtin_amdgcn_exp2f(sacc[0][rf][1]);
      const float p2 = __builtin_amdgcn_exp2f(sacc[0][rf][2]);
      const float p3 = __builtin_amdgcn_exp2f(sacc[0][rf][3]);
      const float p4 = __builtin_amdgcn_exp2f(sacc[1][rf][0]);
      const float p5 = __builtin_amdgcn_exp2f(sacc[1][rf][1]);
      const float p6 = __builtin_amdgcn_exp2f(sacc[1][rf][2]);
      const float p7 = __builtin_amdgcn_exp2f(sacc[1][rf][3]);
      plsum[rf] += ((p0 + p1) + (p2 + p3)) + ((p4 + p5) + (p6 + p7));
      uint4v pw;
      pw.x = __builtin_bit_cast(unsigned int, __builtin_amdgcn_cvt_pkrtz(p0, p1));
      pw.y = __builtin_bit_cast(unsigned int, __builtin_amdgcn_cvt_pkrtz(p2, p3));
      pw.z = __builtin_bit_cast(unsigned int, __builtin_amdgcn_cvt_pkrtz(p4, p5));
      pw.w = __builtin_bit_cast(unsigned int, __builtin_amdgcn_cvt_pkrtz(p6, p7));
      const f16x8 pf = __builtin_bit_cast(f16x8, pw);
      __builtin_amdgcn_s_setprio(1);
#pragma unroll
      for (int nd = 0; nd < 4; ++nd)
        oacc[rf][nd] = MFMAH32(pf, __builtin_bit_cast(f16x8, vraw[nd]), oacc[rf][nd]);
      __builtin_amdgcn_s_setprio(0);
    }
  }

  // drain in-flight dup DMAs (they write ring slots we are about to reuse)
  WAIT_VM0();
  __syncthreads();

  // reduce partial row sums across quads: lane l15 -> sum for qrow rf*16+l15
#pragma unroll
  for (int rf = 0; rf < 2; ++rf) {
    plsum[rf] += __shfl_xor(plsum[rf], 16);
    plsum[rf] += __shfl_xor(plsum[rf], 32);
  }

  float* cbuf = (float*)smem;          // [128 rows][68]
  float* lbuf = cbuf + 128 * 68;       // [128]
  if (par) {
#pragma unroll
    for (int rf = 0; rf < 2; ++rf) {
#pragma unroll
      for (int nd = 0; nd < 4; ++nd)
#pragma unroll
        for (int i = 0; i < 4; ++i)
          cbuf[(pair * 32 + rf * 16 + quad * 4 + i) * 68 + nd * 16 + l15] = oacc[rf][nd][i];
      if (quad == 0) lbuf[pair * 32 + rf * 16 + l15] = plsum[rf];
    }
  }
  __syncthreads();
  if (!par) {
    const int b = bh >> 3, h = bh & 7;
#pragma unroll
    for (int rf = 0; rf < 2; ++rf) {
      const float tot = plsum[rf] + lbuf[pair * 32 + rf * 16 + l15];
      float inv[4];
#pragma unroll
      for (int i = 0; i < 4; ++i)
        inv[i] = __builtin_amdgcn_rcpf(__shfl(tot, quad * 4 + i));
#pragma unroll
      for (int nd = 0; nd < 4; ++nd)
#pragma unroll
        for (int i = 0; i < 4; ++i) {
          const float v = (oacc[rf][nd][i] +
                           cbuf[(pair * 32 + rf * 16 + quad * 4 + i) * 68 + nd * 16 + l15]) * inv[i];
          const int s = rowbase + rf * 16 + quad * 4 + i;
          const int d = nd * 16 + l15;
          ctx[((size_t)(b * 2048 + s) << 9) + h * 64 + d] = f2bf(v);
        }
    }
  }
}

// ---------------------------------------------------------------- out GEMM
// NEW (r10): same 128x64 tile, grid 512, ring-3, vmcnt(3) — but 512-thread
// blocks (8 waves x 16 rows, acc[4]) => 16 waves/CU = 4 waves/SIMD (was 2).
// Isolates occupancy from r5's confounded 64x64 test. Staging re-derived for
// 512 threads: A-slot = ONE width-16 gl_lds (tid covers 128 rows, chunk tid&3,
// same (row>>1)&3 chunk-swizzle); B-slot (4KB) = TWO width-4 gl_lds (per-thread
// issues stay uniform 3/slot -> vmcnt(3) accounting identical to r4's).
__global__ __launch_bounds__(512, 2)
void out_gemm(const u16* __restrict__ A, const u16* __restrict__ W,
              const float* __restrict__ bias, float* __restrict__ out) {
  __shared__ u16 sA[3][4096];
  __shared__ u16 sB[3][2048];
  const int tid = threadIdx.x;          // 0..511
  const int lane = tid & 63;
  const int wave = tid >> 6;            // 0..7
  const int l15 = lane & 15;
  const int quad = lane >> 4;

  const int L = blockIdx.x;
  const int xcd = L & 7;
  const int slot = L >> 3;
  const int bm = xcd * 8 + (slot & 7);
  const int bn = slot >> 3;

  // A staging: one width-16 issue/slot; LDS[r*32 + c*8] = A[bm*128+r][k0+(c^((r>>1)&3))*8]
  const int srow = tid >> 2;            // 0..127
  const int sg = (tid & 3) ^ ((srow >> 1) & 3);
  const u16* gA = A + (bm * 128 + srow) * 512 + sg * 8;
  // B staging: two width-4 issues/slot; issue j covers LDS u16 offsets j*1024 + tid*2.
  // o = j*1024 + tid*2: r = o>>5, cc = (o>>3)&3, e = o&7 (even);
  // src u16-in-row = (cc^((r>>1)&3))*8 + e  (4B-aligned: e even).
  int bsrc[2], bdst[2];
#pragma unroll
  for (int j = 0; j < 2; ++j) {
    const int o = j * 1024 + tid * 2;
    const int r = o >> 5;
    const int cc = (o >> 3) & 3;
    const int e = o & 7;
    bsrc[j] = (bn * 64 + r) * 512 + ((cc ^ ((r >> 1) & 3)) * 8 + e);
    bdst[j] = o;
  }

  const int fsw = (quad ^ ((l15 >> 1) & 3)) * 8;
  const int aoff = (wave * 16 + l15) * 32 + fsw;   // (row>>1)&3 == (l15>>1)&3
  int boff[4];
#pragma unroll
  for (int t = 0; t < 4; ++t) boff[t] = (t * 16 + l15) * 32 + fsw;

  f32x4 acc[4] = {};

#pragma unroll
  for (int t = 0; t < 2; ++t) {
    const int k0 = t * 32;
    gl_lds16(gA + k0, &sA[t][tid * 8 - tid * 8 + (tid * 8)]);  // linear tid*8
#pragma unroll
    for (int j = 0; j < 2; ++j)
      gl_lds4(W + bsrc[j] + k0, &sB[t][bdst[j]]);
  }

  for (int kk = 0; kk < 16; ++kk) {
    WAIT_VM3();
    PIPE_BARRIER();
    {
      const int tp = (kk + 2 < 16) ? kk + 2 : 15;
      const int ns = (kk + 2) % 3;
      const int k0 = tp * 32;
      gl_lds16(gA + k0, &sA[ns][tid * 8]);
#pragma unroll
      for (int j = 0; j < 2; ++j)
        gl_lds4(W + bsrc[j] + k0, &sB[ns][bdst[j]]);
    }
    const int cur = kk % 3;
    short8 af, bf[4];
    af = *(const short8*)&sA[cur][aoff];
#pragma unroll
    for (int t = 0; t < 4; ++t) bf[t] = *(const short8*)&sB[cur][boff[t]];
#pragma unroll
    for (int ni = 0; ni < 4; ++ni)
      acc[ni] = MFMA16(af, bf[ni], acc[ni]);
  }

#pragma unroll
  for (int ni = 0; ni < 4; ++ni) {
    const int col = bn * 64 + ni * 16 + l15;
    const float bs = bias[col];
#pragma unroll
    for (int i = 0; i < 4; ++i) {
      const int row = bm * 128 + wave * 16 + quad * 4 + i;
      out[(size_t)row * 512 + col] = acc[ni][i] + bs;
    }
  }
}

// ---------------------------------------------------------------- launch
extern "C" void kernel_launch(void* const* d_in, const int* in_sizes, int n_in,
                              void* d_out, int out_size, void* d_ws, size_t ws_size,
                              hipStream_t stream) {
  const float* x = (const float*)d_in[0];
  const float* Wq = (const float*)d_in[1];
  const float* bq = (const float*)d_in[2];
  const float* Wk = (const float*)d_in[3];
  const float* bk = (const float*)d_in[4];
  const float* Wv = (const float*)d_in[5];
  const float* bv = (const float*)d_in[6];
  const float* Wo = (const float*)d_in[7];
  const float* bo = (const float*)d_in[8];
  float* out = (float*)d_out;

  char* ws = (char*)d_ws;
  u16* xb  = (u16*)(ws);                               // 8 MiB
  u16* wqb = (u16*)(ws + (8u << 20));                  // 512 KiB each
  u16* wkb = (u16*)(ws + (8u << 20) + (512u << 10));
  u16* wvb = (u16*)(ws + (9u << 20));
  u16* wob = (u16*)(ws + (9u << 20) + (512u << 10));
  u16* Qb  = (u16*)(ws + (10u << 20));                 // 8 MiB [B,H,S,D] bf16 * log2e/8
  u16* Kb  = (u16*)(ws + (18u << 20));                 // 8 MiB [B,H,S,D] bf16
  u16* Vtb = (u16*)(ws + (26u << 20));                 // 8 MiB [B,H,D,S] f16
  u16* ctx = (u16*)(ws + (34u << 20));                 // 8 MiB [B,S,HID] bf16

  prep<<<2560, 256, 0, stream>>>(x, Wq, Wk, Wv, Wo, xb, wqb, wkb, wvb, wob);
  qkv_gemm<<<768, 256, 0, stream>>>(xb, wqb, wkb, wvb, bq, bk, bv, Qb, Kb, Vtb);
  attn<<<512, 512, 0, stream>>>(Qb, Kb, Vtb, ctx);
  out_gemm<<<512, 512, 0, stream>>>(ctx, wob, bo, out);
}